// Round 7
// baseline (566.195 us; speedup 1.0000x reference)
//
#include <hip/hip_runtime.h>
#include <hip/hip_bf16.h>

typedef __bf16 bf16;
typedef __attribute__((ext_vector_type(8)))  __bf16 bf16x8;
typedef __attribute__((ext_vector_type(4)))  __bf16 bf16x4;
typedef __attribute__((ext_vector_type(4)))  float  f32x4;

#define SEQ   2048
#define NDIM  256
#define NH3   48
#define CH    64
#define SPS   72     // sP row stride (bf16 elems; 144B rows, 16B-aligned)
#define VTS   2176   // g_vt row stride (4352B = 17 x 256B sectors)

// canonical bf16 input arena offsets (elements; multiples of 8 -> 16B aligned)
#define OFF_NODES 0
#define OFF_POS   524288
#define OFF_ROT   536576
#define OFF_WN    544768
#define OFF_BN    1069056
#define OFF_WP    1071104
#define OFF_BP    1083392
#define OFF_WR    1085440
#define OFF_WV    1093632
#define OFF_BV    4239360
#define TOT_IN    4251648

__device__ bf16 g_in[TOT_IN];              // 8.5 MB canonical bf16 inputs
__device__ bf16 g_k [NH3 * SEQ * CH];      // [h][s][c] 12.6 MB
__device__ bf16 g_q [NH3 * SEQ * CH];      // [h][s][c] 12.6 MB
__device__ bf16 g_vt[NH3 * NDIM * VTS];    // [h][d][j'] padded rows, j-permuted per 64-block
__device__ int  g_isf32;

// ---------------------------------------------------------------- dtype probe
__global__ __launch_bounds__(256) void detect_k(const unsigned short* __restrict__ p) {
    __shared__ int cff, czero;
    if (threadIdx.x == 0) { cff = 0; czero = 0; }
    __syncthreads();
    int ff = 0, zz = 0;
    for (int r = 0; r < 64; ++r) {
        int idx = threadIdx.x * 64 + r;
        unsigned short u = p[idx];
        if (((u >> 7) & 0xFF) == 0xFF) ff++;
        if (((idx & 1) == 0) && (u == 0)) zz++;
    }
    if (ff) atomicAdd(&cff, ff);
    if (zz) atomicAdd(&czero, zz);
    __syncthreads();
    if (threadIdx.x == 0) g_isf32 = (cff > 2 || czero > 6000) ? 1 : 0;
}

// --------------------------------------------------------- input canonicalize
__global__ __launch_bounds__(256) void convert_k(
    const void* s0, const void* s1, const void* s2, const void* s3, const void* s4,
    const void* s5, const void* s6, const void* s7, const void* s8, const void* s9)
{
    const void* srcs[10] = {s0, s1, s2, s3, s4, s5, s6, s7, s8, s9};
    const int   szs[10]  = {524288, 12288, 8192, 524288, 2048, 12288, 2048, 8192, 3145728, 12288};
    const int   offs[10] = {OFF_NODES, OFF_POS, OFF_ROT, OFF_WN, OFF_BN,
                            OFF_WP, OFF_BP, OFF_WR, OFF_WV, OFF_BV};
    const int y = blockIdx.y;
    const void* src = srcs[y];
    bf16* dst = g_in + offs[y];
    const int n = szs[y];
    const int isf = g_isf32;
    const int stride = gridDim.x * 256 * 4;
    for (int i = (blockIdx.x * 256 + threadIdx.x) * 4; i < n; i += stride) {
        bf16x4 o;
        if (isf) {
            float4 v = *(const float4*)((const float*)src + i);
            o[0] = (bf16)v.x; o[1] = (bf16)v.y; o[2] = (bf16)v.z; o[3] = (bf16)v.w;
        } else {
            o = *(const bf16x4*)((const bf16*)src + i);
        }
        *(bf16x4*)(dst + i) = o;
    }
}

// ------------------------------------------------- nodes -> k,q (heads 0-15)
__global__ __launch_bounds__(256) void proj_nodes_kq()
{
    __shared__ __align__(16) bf16 sB[64 * 264];
    const bf16* nodes = g_in + OFF_NODES;
    const bf16* Wn    = g_in + OFF_WN;
    const bf16* bn    = g_in + OFF_BN;
    const int t  = threadIdx.x;
    const int s0 = blockIdx.x * 64;
    const int f0 = blockIdx.y * 64;

    for (int rep = 0; rep < 8; ++rep) {
        int idx = t + rep * 256;
        int row = idx >> 5, chunk = idx & 31;
        *(bf16x8*)&sB[row * 264 + chunk * 8] =
            *(const bf16x8*)&Wn[(f0 + row) * 256 + chunk * 8];
    }
    __syncthreads();

    const int w = t >> 6, lane = t & 63;
    const int l15 = lane & 15, quad = lane >> 4;

    f32x4 acc[4] = {{}, {}, {}, {}};
    const bf16* arow = nodes + (s0 + w * 16 + l15) * 256 + quad * 8;
#pragma unroll
    for (int kc = 0; kc < 8; ++kc) {
        bf16x8 af = *(const bf16x8*)(arow + kc * 32);
#pragma unroll
        for (int ft = 0; ft < 4; ++ft) {
            bf16x8 bfr = *(const bf16x8*)&sB[(ft * 16 + l15) * 264 + kc * 32 + quad * 8];
            acc[ft] = __builtin_amdgcn_mfma_f32_16x16x32_bf16(af, bfr, acc[ft], 0, 0, 0);
        }
    }
#pragma unroll
    for (int ft = 0; ft < 4; ++ft) {
        int f = f0 + ft * 16 + l15;
        float bias = (float)bn[f];
        int h = f >> 7, c2 = f & 127;
        bf16* base = (c2 < 64) ? (g_k + h * SEQ * CH + c2)
                               : (g_q + h * SEQ * CH + (c2 - 64));
#pragma unroll
        for (int r = 0; r < 4; ++r) {
            int s = s0 + w * 16 + quad * 4 + r;
            base[s * CH] = (bf16)(acc[ft][r] + bias);
        }
    }
}

// ------------------------------------- pos/rot -> k,q (heads 16-31 / 32-47)
__global__ __launch_bounds__(256) void proj_posrot_kq()
{
    const bf16* pos  = g_in + OFF_POS;
    const bf16* rotq = g_in + OFF_ROT;
    const bf16* Wp   = g_in + OFF_WP;
    const bf16* bp   = g_in + OFF_BP;
    const bf16* Wr   = g_in + OFF_WR;
    int id = blockIdx.x * 256 + threadIdx.x;
    int f  = id & 2047;
    int s  = (id >> 11) & 2047;
    int src = id >> 22;
    float y; int h;
    if (src == 0) {
        float a = (float)bp[f];
#pragma unroll
        for (int x = 0; x < 6; ++x) a += (float)pos[s * 6 + x] * (float)Wp[f * 6 + x];
        y = a; h = 16 + (f >> 7);
    } else {
        float a = 0.f;
#pragma unroll
        for (int x = 0; x < 4; ++x) a += (float)rotq[s * 4 + x] * (float)Wr[f * 4 + x];
        y = a; h = 32 + (f >> 7);
    }
    int c2 = f & 127;
    if (c2 < 64) g_k[(h * SEQ + s) * CH + c2]        = (bf16)y;
    else         g_q[(h * SEQ + s) * CH + (c2 - 64)] = (bf16)y;
}

// ----------------------- nodes -> V (transposed + j-permuted, padded stride)
__global__ __launch_bounds__(256) void proj_v()
{
    __shared__ __align__(16) bf16 sB[64 * 264];
    __shared__ __align__(16) bf16 sO[64 * 72];
    const bf16* nodes = g_in + OFF_NODES;
    const bf16* Wv    = g_in + OFF_WV;
    const bf16* bv    = g_in + OFF_BV;
    const int t  = threadIdx.x;
    const int s0 = blockIdx.x * 64;
    const int f0 = blockIdx.y * 64;

    for (int rep = 0; rep < 8; ++rep) {
        int idx = t + rep * 256;
        int row = idx >> 5, chunk = idx & 31;
        *(bf16x8*)&sB[row * 264 + chunk * 8] =
            *(const bf16x8*)&Wv[(f0 + row) * 256 + chunk * 8];
    }
    __syncthreads();

    const int w = t >> 6, lane = t & 63;
    const int l15 = lane & 15, quad = lane >> 4;

    f32x4 acc[4] = {{}, {}, {}, {}};
    const bf16* arow = nodes + (s0 + w * 16 + l15) * 256 + quad * 8;
#pragma unroll
    for (int kc = 0; kc < 8; ++kc) {
        bf16x8 af = *(const bf16x8*)(arow + kc * 32);
#pragma unroll
        for (int ft = 0; ft < 4; ++ft) {
            bf16x8 bfr = *(const bf16x8*)&sB[(ft * 16 + l15) * 264 + kc * 32 + quad * 8];
            acc[ft] = __builtin_amdgcn_mfma_f32_16x16x32_bf16(af, bfr, acc[ft], 0, 0, 0);
        }
    }
    __syncthreads();
#pragma unroll
    for (int ft = 0; ft < 4; ++ft) {
        int n = f0 + ft * 16 + l15;
        float bias = (float)bv[n];
#pragma unroll
        for (int r = 0; r < 4; ++r) {
            // s-local l = w*16+quad*4+r -> j' = (quad*4+r)*4 + w
            sO[(ft * 16 + l15) * 72 + (quad * 4 + r) * 4 + w] = (bf16)(acc[ft][r] + bias);
        }
    }
    __syncthreads();
    for (int rep = 0; rep < 2; ++rep) {
        int idx = t + rep * 256;
        int row = idx >> 3, chunk = idx & 7;
        *(bf16x8*)&g_vt[(size_t)(f0 + row) * VTS + s0 + chunk * 8] =
            *(const bf16x8*)&sO[row * 72 + chunk * 8];
    }
}

// ---------------------------------------------------------------- zero d_out
__global__ __launch_bounds__(256) void zero_out_k(float* __restrict__ out) {
    int idx = (blockIdx.x * 256 + threadIdx.x) * 4;
    f32x4 z = {0.f, 0.f, 0.f, 0.f};
    *(f32x4*)&out[idx] = z;
}

// ------------------------------------------------------------- attention
// 512 threads (8 waves), Bi=128 i-rows per block. XCD head-clustering:
// bx&7 = XCD (HW round-robin dispatch), each XCD owns 6 heads so its L2
// retains those heads' V/Q across i-tile blocks.
// S phase: wave w computes i-rows w*16..+16 x 64 j (K frags in regs).
// PV phase: wave w = (i-half w>>2, d-quarter w&3): 64 i x 64 d, acc 64 VGPR.
__global__ __launch_bounds__(512, 4) void attn_k(float* __restrict__ out)
{
    const int bx  = blockIdx.x;
    const int xcd = bx & 7;
    const int sub = bx >> 3;             // 0..95
    const int h   = xcd * 6 + (sub % 6); // 6 heads per XCD
    const int it  = sub / 6;             // 0..15
    const int i0  = it * 128;
    const int t   = threadIdx.x;
    const int w   = t >> 6, lane = t & 63;
    const int l15 = lane & 15, quad = lane >> 4;
    const bool rot = (h >= 32);

    __shared__ __align__(16) bf16 sP[2][128 * SPS];   // 36864 B
    __shared__ float sL[128];

    const bf16* kb = g_k  + h * SEQ * CH;
    const bf16* qb = g_q  + h * SEQ * CH;
    const bf16* vb = g_vt + (size_t)h * NDIM * VTS;

    // K fragments: wave w owns S-rows i0 + w*16 .. +16
    bf16x8 kf0 = *(const bf16x8*)&kb[(i0 + w * 16 + l15) * CH + quad * 8];
    bf16x8 kf1 = *(const bf16x8*)&kb[(i0 + w * 16 + l15) * CH + 32 + quad * 8];

    // PV split: i-half ih = w>>2 (64 rows), d-quarter dq = w&3 (64 cols)
    const int ih = w >> 2, dq = w & 3;

    int qo[4], vo[4];
#pragma unroll
    for (int jb = 0; jb < 4; ++jb) qo[jb] = (jb * 16 + l15) * CH + quad * 8;
#pragma unroll
    for (int dt = 0; dt < 4; ++dt) vo[dt] = (dq * 64 + dt * 16 + l15) * VTS + quad * 8;

    f32x4 acc[4][4];
#pragma unroll
    for (int a = 0; a < 4; ++a)
#pragma unroll
        for (int b = 0; b < 4; ++b) acc[a][b] = (f32x4){0.f, 0.f, 0.f, 0.f};
    f32x4 lp = {0.f, 0.f, 0.f, 0.f};

    for (int st = 0; st < 32; ++st) {
        bf16* sp = sP[st & 1];
        const bf16* qbj = qb + st * (64 * CH);
        const bf16* vbj = vb + st * 64;

        // S phase: 16 i-rows x 64 j per wave
        bf16x8 q0[4], q1[4];
#pragma unroll
        for (int jb = 0; jb < 4; ++jb) {
            q0[jb] = *(const bf16x8*)&qbj[qo[jb]];
            q1[jb] = *(const bf16x8*)&qbj[qo[jb] + 32];
        }
        f32x4 sjb[4];
#pragma unroll
        for (int jb = 0; jb < 4; ++jb) {
            f32x4 sa = {};
            sa = __builtin_amdgcn_mfma_f32_16x16x32_bf16(kf0, q0[jb], sa, 0, 0, 0);
            sa = __builtin_amdgcn_mfma_f32_16x16x32_bf16(kf1, q1[jb], sa, 0, 0, 0);
            sjb[jb] = sa;
        }

        // V kc0 loads in flight across P + barrier
        bf16x8 vf0[4];
#pragma unroll
        for (int dt = 0; dt < 4; ++dt) vf0[dt] = *(const bf16x8*)&vbj[vo[dt]];

        // P phase: exp + pack; column j' = l15*4 + jb (logical j = jb*16+l15)
#pragma unroll
        for (int r = 0; r < 4; ++r) {
            bf16x4 pk;
#pragma unroll
            for (int jb = 0; jb < 4; ++jb) {
                float d = sjb[jb][r];
                float x = rot ? (d * d * 0.25f) : (d * 0.25f);
                x = fminf(x, 60.f);
                float p = __expf(x);
                lp[r] += p;
                pk[jb] = (bf16)p;
            }
            *(bf16x4*)&sp[(w * 16 + quad * 4 + r) * SPS + l15 * 4] = pk;
        }
        __syncthreads();

        // V kc1 loads in flight across PV kc0
        bf16x8 vf1[4];
#pragma unroll
        for (int dt = 0; dt < 4; ++dt) vf1[dt] = *(const bf16x8*)&vbj[vo[dt] + 32];

        bf16x8 ap[4];
#pragma unroll
        for (int itr = 0; itr < 4; ++itr)
            ap[itr] = *(const bf16x8*)&sp[(ih * 64 + itr * 16 + l15) * SPS + quad * 8];
#pragma unroll
        for (int itr = 0; itr < 4; ++itr)
#pragma unroll
            for (int dt = 0; dt < 4; ++dt)
                acc[itr][dt] = __builtin_amdgcn_mfma_f32_16x16x32_bf16(
                    ap[itr], vf0[dt], acc[itr][dt], 0, 0, 0);
#pragma unroll
        for (int itr = 0; itr < 4; ++itr)
            ap[itr] = *(const bf16x8*)&sp[(ih * 64 + itr * 16 + l15) * SPS + 32 + quad * 8];
#pragma unroll
        for (int itr = 0; itr < 4; ++itr)
#pragma unroll
            for (int dt = 0; dt < 4; ++dt)
                acc[itr][dt] = __builtin_amdgcn_mfma_f32_16x16x32_bf16(
                    ap[itr], vf1[dt], acc[itr][dt], 0, 0, 0);
    }

    // l reduce across the 16 j-lanes (wave w owns S-rows w*16..+16)
#pragma unroll
    for (int off = 1; off < 16; off <<= 1) {
#pragma unroll
        for (int r = 0; r < 4; ++r) lp[r] += __shfl_xor(lp[r], off, 64);
    }
    if (l15 == 0) *(f32x4*)&sL[w * 16 + quad * 4] = lp;
    __syncthreads();

    // normalize + accumulate over heads into f32 output
#pragma unroll
    for (int itr = 0; itr < 4; ++itr) {
        f32x4 lv = *(const f32x4*)&sL[ih * 64 + itr * 16 + quad * 4];
#pragma unroll
        for (int r = 0; r < 4; ++r) {
            float inv = 1.0f / lv[r];
            float* ob = &out[(i0 + ih * 64 + itr * 16 + quad * 4 + r) * NDIM + dq * 64 + l15];
#pragma unroll
            for (int dt = 0; dt < 4; ++dt)
                atomicAdd(ob + dt * 16, acc[itr][dt][r] * inv);
        }
    }
}

extern "C" void kernel_launch(void* const* d_in, const int* in_sizes, int n_in,
                              void* d_out, int out_size, void* d_ws, size_t ws_size,
                              hipStream_t stream) {
    detect_k <<<dim3(1),        dim3(256), 0, stream>>>((const unsigned short*)d_in[8]);
    convert_k<<<dim3(768, 10),  dim3(256), 0, stream>>>(d_in[0], d_in[1], d_in[2], d_in[3],
                                                        d_in[4], d_in[5], d_in[6], d_in[7],
                                                        d_in[8], d_in[9]);
    proj_nodes_kq <<<dim3(32, 32),  dim3(256), 0, stream>>>();
    proj_posrot_kq<<<dim3(32768),   dim3(256), 0, stream>>>();
    proj_v        <<<dim3(32, 192), dim3(256), 0, stream>>>();
    zero_out_k    <<<dim3(512),     dim3(256), 0, stream>>>((float*)d_out);
    attn_k        <<<dim3(768),     dim3(512), 0, stream>>>((float*)d_out);
}

// Round 8
// 447.280 us; speedup vs baseline: 1.2659x; 1.2659x over previous
//
#include <hip/hip_runtime.h>
#include <hip/hip_bf16.h>

typedef __bf16 bf16;
typedef __attribute__((ext_vector_type(8)))  __bf16 bf16x8;
typedef __attribute__((ext_vector_type(4)))  __bf16 bf16x4;
typedef __attribute__((ext_vector_type(4)))  float  f32x4;

#define SEQ   2048
#define NDIM  256
#define NH3   48
#define CH    64
#define SPS   72     // sP row stride (bf16 elems; 144B rows, 16B-aligned)
#define VTS   2176   // g_vt row stride (4352B = 17 x 256B sectors)

// canonical bf16 input arena offsets (elements; multiples of 8 -> 16B aligned)
#define OFF_NODES 0
#define OFF_POS   524288
#define OFF_ROT   536576
#define OFF_WN    544768
#define OFF_BN    1069056
#define OFF_WP    1071104
#define OFF_BP    1083392
#define OFF_WR    1085440
#define OFF_WV    1093632
#define OFF_BV    4239360
#define TOT_IN    4251648

__device__ bf16 g_in[TOT_IN];              // 8.5 MB canonical bf16 inputs
__device__ bf16 g_k [NH3 * SEQ * CH];      // [h][s][c] 12.6 MB
__device__ bf16 g_q [NH3 * SEQ * CH];      // [h][s][c] 12.6 MB
__device__ bf16 g_vt[NH3 * NDIM * VTS];    // [h][d][j'] padded rows, j-permuted per 64-block
__device__ int  g_isf32;

// ---------------------------------------------------------------- dtype probe
__global__ __launch_bounds__(256) void detect_k(const unsigned short* __restrict__ p) {
    __shared__ int cff, czero;
    if (threadIdx.x == 0) { cff = 0; czero = 0; }
    __syncthreads();
    int ff = 0, zz = 0;
    for (int r = 0; r < 64; ++r) {
        int idx = threadIdx.x * 64 + r;
        unsigned short u = p[idx];
        if (((u >> 7) & 0xFF) == 0xFF) ff++;
        if (((idx & 1) == 0) && (u == 0)) zz++;
    }
    if (ff) atomicAdd(&cff, ff);
    if (zz) atomicAdd(&czero, zz);
    __syncthreads();
    if (threadIdx.x == 0) g_isf32 = (cff > 2 || czero > 6000) ? 1 : 0;
}

// --------------------------------------------------------- input canonicalize
__global__ __launch_bounds__(256) void convert_k(
    const void* s0, const void* s1, const void* s2, const void* s3, const void* s4,
    const void* s5, const void* s6, const void* s7, const void* s8, const void* s9)
{
    const void* srcs[10] = {s0, s1, s2, s3, s4, s5, s6, s7, s8, s9};
    const int   szs[10]  = {524288, 12288, 8192, 524288, 2048, 12288, 2048, 8192, 3145728, 12288};
    const int   offs[10] = {OFF_NODES, OFF_POS, OFF_ROT, OFF_WN, OFF_BN,
                            OFF_WP, OFF_BP, OFF_WR, OFF_WV, OFF_BV};
    const int y = blockIdx.y;
    const void* src = srcs[y];
    bf16* dst = g_in + offs[y];
    const int n = szs[y];
    const int isf = g_isf32;
    const int stride = gridDim.x * 256 * 4;
    for (int i = (blockIdx.x * 256 + threadIdx.x) * 4; i < n; i += stride) {
        bf16x4 o;
        if (isf) {
            float4 v = *(const float4*)((const float*)src + i);
            o[0] = (bf16)v.x; o[1] = (bf16)v.y; o[2] = (bf16)v.z; o[3] = (bf16)v.w;
        } else {
            o = *(const bf16x4*)((const bf16*)src + i);
        }
        *(bf16x4*)(dst + i) = o;
    }
}

// ------------------------------------------------- nodes -> k,q (heads 0-15)
__global__ __launch_bounds__(256) void proj_nodes_kq()
{
    __shared__ __align__(16) bf16 sB[64 * 264];
    const bf16* nodes = g_in + OFF_NODES;
    const bf16* Wn    = g_in + OFF_WN;
    const bf16* bn    = g_in + OFF_BN;
    const int t  = threadIdx.x;
    const int s0 = blockIdx.x * 64;
    const int f0 = blockIdx.y * 64;

    for (int rep = 0; rep < 8; ++rep) {
        int idx = t + rep * 256;
        int row = idx >> 5, chunk = idx & 31;
        *(bf16x8*)&sB[row * 264 + chunk * 8] =
            *(const bf16x8*)&Wn[(f0 + row) * 256 + chunk * 8];
    }
    __syncthreads();

    const int w = t >> 6, lane = t & 63;
    const int l15 = lane & 15, quad = lane >> 4;

    f32x4 acc[4] = {{}, {}, {}, {}};
    const bf16* arow = nodes + (s0 + w * 16 + l15) * 256 + quad * 8;
#pragma unroll
    for (int kc = 0; kc < 8; ++kc) {
        bf16x8 af = *(const bf16x8*)(arow + kc * 32);
#pragma unroll
        for (int ft = 0; ft < 4; ++ft) {
            bf16x8 bfr = *(const bf16x8*)&sB[(ft * 16 + l15) * 264 + kc * 32 + quad * 8];
            acc[ft] = __builtin_amdgcn_mfma_f32_16x16x32_bf16(af, bfr, acc[ft], 0, 0, 0);
        }
    }
#pragma unroll
    for (int ft = 0; ft < 4; ++ft) {
        int f = f0 + ft * 16 + l15;
        float bias = (float)bn[f];
        int h = f >> 7, c2 = f & 127;
        bf16* base = (c2 < 64) ? (g_k + h * SEQ * CH + c2)
                               : (g_q + h * SEQ * CH + (c2 - 64));
#pragma unroll
        for (int r = 0; r < 4; ++r) {
            int s = s0 + w * 16 + quad * 4 + r;
            base[s * CH] = (bf16)(acc[ft][r] + bias);
        }
    }
}

// ------------------------------------- pos/rot -> k,q (heads 16-31 / 32-47)
__global__ __launch_bounds__(256) void proj_posrot_kq()
{
    const bf16* pos  = g_in + OFF_POS;
    const bf16* rotq = g_in + OFF_ROT;
    const bf16* Wp   = g_in + OFF_WP;
    const bf16* bp   = g_in + OFF_BP;
    const bf16* Wr   = g_in + OFF_WR;
    int id = blockIdx.x * 256 + threadIdx.x;
    int f  = id & 2047;
    int s  = (id >> 11) & 2047;
    int src = id >> 22;
    float y; int h;
    if (src == 0) {
        float a = (float)bp[f];
#pragma unroll
        for (int x = 0; x < 6; ++x) a += (float)pos[s * 6 + x] * (float)Wp[f * 6 + x];
        y = a; h = 16 + (f >> 7);
    } else {
        float a = 0.f;
#pragma unroll
        for (int x = 0; x < 4; ++x) a += (float)rotq[s * 4 + x] * (float)Wr[f * 4 + x];
        y = a; h = 32 + (f >> 7);
    }
    int c2 = f & 127;
    if (c2 < 64) g_k[(h * SEQ + s) * CH + c2]        = (bf16)y;
    else         g_q[(h * SEQ + s) * CH + (c2 - 64)] = (bf16)y;
}

// ----------------------- nodes -> V (transposed + j-permuted, padded stride)
__global__ __launch_bounds__(256) void proj_v()
{
    __shared__ __align__(16) bf16 sB[64 * 264];
    __shared__ __align__(16) bf16 sO[64 * 72];
    const bf16* nodes = g_in + OFF_NODES;
    const bf16* Wv    = g_in + OFF_WV;
    const bf16* bv    = g_in + OFF_BV;
    const int t  = threadIdx.x;
    const int s0 = blockIdx.x * 64;
    const int f0 = blockIdx.y * 64;

    for (int rep = 0; rep < 8; ++rep) {
        int idx = t + rep * 256;
        int row = idx >> 5, chunk = idx & 31;
        *(bf16x8*)&sB[row * 264 + chunk * 8] =
            *(const bf16x8*)&Wv[(f0 + row) * 256 + chunk * 8];
    }
    __syncthreads();

    const int w = t >> 6, lane = t & 63;
    const int l15 = lane & 15, quad = lane >> 4;

    f32x4 acc[4] = {{}, {}, {}, {}};
    const bf16* arow = nodes + (s0 + w * 16 + l15) * 256 + quad * 8;
#pragma unroll
    for (int kc = 0; kc < 8; ++kc) {
        bf16x8 af = *(const bf16x8*)(arow + kc * 32);
#pragma unroll
        for (int ft = 0; ft < 4; ++ft) {
            bf16x8 bfr = *(const bf16x8*)&sB[(ft * 16 + l15) * 264 + kc * 32 + quad * 8];
            acc[ft] = __builtin_amdgcn_mfma_f32_16x16x32_bf16(af, bfr, acc[ft], 0, 0, 0);
        }
    }
    __syncthreads();
#pragma unroll
    for (int ft = 0; ft < 4; ++ft) {
        int n = f0 + ft * 16 + l15;
        float bias = (float)bv[n];
#pragma unroll
        for (int r = 0; r < 4; ++r) {
            // s-local l = w*16+quad*4+r -> j' = (quad*4+r)*4 + w
            sO[(ft * 16 + l15) * 72 + (quad * 4 + r) * 4 + w] = (bf16)(acc[ft][r] + bias);
        }
    }
    __syncthreads();
    for (int rep = 0; rep < 2; ++rep) {
        int idx = t + rep * 256;
        int row = idx >> 3, chunk = idx & 7;
        *(bf16x8*)&g_vt[(size_t)(f0 + row) * VTS + s0 + chunk * 8] =
            *(const bf16x8*)&sO[row * 72 + chunk * 8];
    }
}

// ---------------------------------------------------------------- zero d_out
__global__ __launch_bounds__(256) void zero_out_k(float* __restrict__ out) {
    int idx = (blockIdx.x * 256 + threadIdx.x) * 4;
    f32x4 z = {0.f, 0.f, 0.f, 0.f};
    *(f32x4*)&out[idx] = z;
}

// ------------------------------------------------------------- attention
// 512 threads (8 waves), Bi=128. XCD head-clustering (6 heads per XCD).
// Per step: stage Q(8KB)+V(32KB) into LDS with COALESCED loads (each byte
// crosses L1 once), then S from sQ (K in regs), P into sP, PV from sP+sV.
// 3 barriers/step, all buffers single. LDS 58.5KB -> 2 blocks/CU.
__global__ __launch_bounds__(512, 4) void attn_k(float* __restrict__ out)
{
    const int bx  = blockIdx.x;
    const int xcd = bx & 7;
    const int sub = bx >> 3;             // 0..95
    const int h   = xcd * 6 + (sub % 6); // 6 heads per XCD
    const int it  = sub / 6;             // 0..15
    const int i0  = it * 128;
    const int t   = threadIdx.x;
    const int w   = t >> 6, lane = t & 63;
    const int l15 = lane & 15, quad = lane >> 4;
    const bool rot = (h >= 32);

    __shared__ __align__(16) bf16 sQ[64 * 64];       //  8192 B
    __shared__ __align__(16) bf16 sV[256 * 64];      // 32768 B (stride 64, no pad)
    __shared__ __align__(16) bf16 sP[128 * SPS];     // 18432 B
    __shared__ float sL[128];

    const bf16* kb = g_k  + h * SEQ * CH;
    const bf16* qb = g_q  + h * SEQ * CH;
    const bf16* vb = g_vt + (size_t)h * NDIM * VTS;

    // K fragments: wave w owns S-rows i0 + w*16 .. +16
    bf16x8 kf0 = *(const bf16x8*)&kb[(i0 + w * 16 + l15) * CH + quad * 8];
    bf16x8 kf1 = *(const bf16x8*)&kb[(i0 + w * 16 + l15) * CH + 32 + quad * 8];

    // PV split: i-half ih = w>>2 (64 rows), d-quarter dq = w&3 (64 cols)
    const int ih = w >> 2, dq = w & 3;

    // staging decomposition: 16B chunks; Q: 512 chunks (1/thread); V: 2048 (4/thread)
    const int qrow = t >> 3, qch = t & 7;

    f32x4 acc[4][4];
#pragma unroll
    for (int a = 0; a < 4; ++a)
#pragma unroll
        for (int b = 0; b < 4; ++b) acc[a][b] = (f32x4){0.f, 0.f, 0.f, 0.f};
    f32x4 lp = {0.f, 0.f, 0.f, 0.f};

    for (int st = 0; st < 32; ++st) {
        // ---- stage Q (fully contiguous 8KB) + V (128B row segments)
        *(bf16x8*)&sQ[t * 8] = *(const bf16x8*)&qb[st * 4096 + t * 8];
#pragma unroll
        for (int rep = 0; rep < 4; ++rep) {
            int idx = t + rep * 512;
            int row = idx >> 3, ch = idx & 7;
            *(bf16x8*)&sV[row * 64 + ch * 8] =
                *(const bf16x8*)&vb[(size_t)row * VTS + st * 64 + ch * 8];
        }
        __syncthreads();                               // B1: staging visible

        // ---- S phase: 16 i-rows x 64 j per wave
        f32x4 sjb[4];
#pragma unroll
        for (int jb = 0; jb < 4; ++jb) {
            bf16x8 q0 = *(const bf16x8*)&sQ[(jb * 16 + l15) * 64 + quad * 8];
            bf16x8 q1 = *(const bf16x8*)&sQ[(jb * 16 + l15) * 64 + 32 + quad * 8];
            f32x4 sa = {};
            sa = __builtin_amdgcn_mfma_f32_16x16x32_bf16(kf0, q0, sa, 0, 0, 0);
            sa = __builtin_amdgcn_mfma_f32_16x16x32_bf16(kf1, q1, sa, 0, 0, 0);
            sjb[jb] = sa;
        }

        // ---- P phase: exp + pack; column j' = l15*4 + jb (logical j = jb*16+l15)
#pragma unroll
        for (int r = 0; r < 4; ++r) {
            bf16x4 pk;
#pragma unroll
            for (int jb = 0; jb < 4; ++jb) {
                float d = sjb[jb][r];
                float x = rot ? (d * d * 0.25f) : (d * 0.25f);
                x = fminf(x, 60.f);
                float p = __expf(x);
                lp[r] += p;
                pk[jb] = (bf16)p;
            }
            *(bf16x4*)&sP[(w * 16 + quad * 4 + r) * SPS + l15 * 4] = pk;
        }
        __syncthreads();                               // B2: sP visible

        // ---- PV phase: wave w owns (ih, dq): 64 i x 64 d
#pragma unroll
        for (int kc = 0; kc < 2; ++kc) {
            bf16x8 ap[4], vf[4];
#pragma unroll
            for (int itr = 0; itr < 4; ++itr)
                ap[itr] = *(const bf16x8*)&sP[(ih * 64 + itr * 16 + l15) * SPS + kc * 32 + quad * 8];
#pragma unroll
            for (int dt = 0; dt < 4; ++dt)
                vf[dt] = *(const bf16x8*)&sV[(dq * 64 + dt * 16 + l15) * 64 + kc * 32 + quad * 8];
#pragma unroll
            for (int itr = 0; itr < 4; ++itr)
#pragma unroll
                for (int dt = 0; dt < 4; ++dt)
                    acc[itr][dt] = __builtin_amdgcn_mfma_f32_16x16x32_bf16(
                        ap[itr], vf[dt], acc[itr][dt], 0, 0, 0);
        }
        __syncthreads();                               // B3: PV done reading
    }

    // l reduce across the 16 j-lanes (wave w owns S-rows w*16..+16)
#pragma unroll
    for (int off = 1; off < 16; off <<= 1) {
#pragma unroll
        for (int r = 0; r < 4; ++r) lp[r] += __shfl_xor(lp[r], off, 64);
    }
    if (l15 == 0) *(f32x4*)&sL[w * 16 + quad * 4] = lp;
    __syncthreads();

    // normalize + accumulate over heads into f32 output
#pragma unroll
    for (int itr = 0; itr < 4; ++itr) {
        f32x4 lv = *(const f32x4*)&sL[ih * 64 + itr * 16 + quad * 4];
#pragma unroll
        for (int r = 0; r < 4; ++r) {
            float inv = 1.0f / lv[r];
            float* ob = &out[(i0 + ih * 64 + itr * 16 + quad * 4 + r) * NDIM + dq * 64 + l15];
#pragma unroll
            for (int dt = 0; dt < 4; ++dt)
                atomicAdd(ob + dt * 16, acc[itr][dt][r] * inv);
        }
    }
}

extern "C" void kernel_launch(void* const* d_in, const int* in_sizes, int n_in,
                              void* d_out, int out_size, void* d_ws, size_t ws_size,
                              hipStream_t stream) {
    detect_k <<<dim3(1),        dim3(256), 0, stream>>>((const unsigned short*)d_in[8]);
    convert_k<<<dim3(768, 10),  dim3(256), 0, stream>>>(d_in[0], d_in[1], d_in[2], d_in[3],
                                                        d_in[4], d_in[5], d_in[6], d_in[7],
                                                        d_in[8], d_in[9]);
    proj_nodes_kq <<<dim3(32, 32),  dim3(256), 0, stream>>>();
    proj_posrot_kq<<<dim3(32768),   dim3(256), 0, stream>>>();
    proj_v        <<<dim3(32, 192), dim3(256), 0, stream>>>();
    zero_out_k    <<<dim3(512),     dim3(256), 0, stream>>>((float*)d_out);
    attn_k        <<<dim3(768),     dim3(512), 0, stream>>>((float*)d_out);
}